// Round 12
// baseline (1014.022 us; speedup 1.0000x reference)
//
#include <hip/hip_runtime.h>

#define FLTMAX 3.402823466e+38f

// ---------- helpers ----------
__device__ inline float b2f(unsigned short u){
    return __uint_as_float(((unsigned int)u) << 16);
}
// flag-dispatched input load: mode=1 -> f32 buffer, mode=0 -> bf16 buffer
__device__ inline float ldin(const void* p, long i, int f32m){
    return f32m ? ((const float*)p)[i] : b2f(((const unsigned short*)p)[i]);
}
__device__ inline int pix_idx(float lx, float ly, float half_, int wh){
    lx = fminf(fmaxf(lx, -1.f), 1.f);
    ly = fminf(fmaxf(ly, -1.f), 1.f);
    int px = (int)rintf((lx + 1.f) * half_ - 0.5f);   // round-half-even = jnp.round
    int py = (int)rintf((ly + 1.f) * half_ - 0.5f);
    px = min(max(px, 0), wh - 1);
    py = min(max(py, 0), wh - 1);
    return py * wh + px;
}
__device__ inline void ins5(float* b5, float d){
    if(d < b5[4]){
        b5[4] = d;
#pragma unroll
        for(int q = 4; q > 0; --q){
            if(b5[q] < b5[q-1]){ float tm = b5[q]; b5[q] = b5[q-1]; b5[q-1] = tm; }
        }
    }
}
// full 5-element sorting network (9 comparators) — sorts ANY order, branchless
__device__ inline void sort5n(float* a){
#define CMPX(i,j){ float lo_=fminf(a[i],a[j]); float hi_=fmaxf(a[i],a[j]); a[i]=lo_; a[j]=hi_; }
    CMPX(0,1) CMPX(3,4) CMPX(2,4) CMPX(2,3) CMPX(0,3) CMPX(0,2) CMPX(1,4) CMPX(1,3) CMPX(1,2)
#undef CMPX
}
__device__ inline float wred_add(float v){
    for(int o = 32; o > 0; o >>= 1) v += __shfl_down(v, o);
    return v;
}

// ---------- dtype auto-detect (64 blocks, atomic count; mode[0] = hit count) ----------
__global__ __launch_bounds__(256) void detect_mode(const void* xraw, int* flag){
    __shared__ int sh[256];
    const unsigned short* p = (const unsigned short*)xraw;
    int t = threadIdx.x, c = 0;
    int base = blockIdx.x * 1024;
    for(int i = base + t; i < base + 1024; i += 256){
        float v = b2f(p[i]);
        if(!(fabsf(v) < 100.f)) c++;
    }
    sh[t] = c;
    __syncthreads();
    for(int s = 128; s > 0; s >>= 1){
        if(t < s) sh[t] += sh[t + s];
        __syncthreads();
    }
    if(t == 0 && sh[0] > 0) atomicAdd(flag, sh[0]);
}
#define GETM(modeptr) (((*(modeptr)) > 64) ? 1 : 0)

// ---------- small utility kernels ----------
__global__ void fill_f32(float* p, float v, int n){
    int i = blockIdx.x * blockDim.x + threadIdx.x;
    if(i < n) p[i] = v;
}

// token2map scatter
__global__ __launch_bounds__(256) void scatter_map(const void* x, const void* loc,
                                                   const int* idx_agg, float* acc, float* cnt,
                                                   const int* mode){
    int m = GETM(mode);
    int bn = blockIdx.x;                 // 0..16383
    int b = bn >> 12;
    float lx = ldin(loc, (long)bn * 2 + 0, m);
    float ly = ldin(loc, (long)bn * 2 + 1, m);
    int p = pix_idx(lx, ly, 32.f, 64);
    int ia = idx_agg[bn] & 4095;
    long src = ((long)(b << 12) + ia) * 256;
    float* dst = acc + ((size_t)(b << 12) + p) * 256;
    int t = threadIdx.x;                 // 256 = C
    unsafeAtomicAdd(&dst[t], ldin(x, src + t, m));
    if(t == 0) unsafeAtomicAdd(&cnt[(b << 12) + p], 1.0f);
}

__global__ void divide_map(float* xmap, const float* cnt, int n){
    int i = blockIdx.x * 256 + threadIdx.x;
    if(i < n) xmap[i] = xmap[i] / (cnt[i >> 8] + 1e-6f);
}

// ---------- conv C init with bias ----------
__global__ void init_convo(float* convo, const void* bias, const int* mode){
    int m = GETM(mode);
    int e = blockIdx.x * 256 + threadIdx.x;   // 2,097,152
    convo[e] = ldin(bias, e & 511, m);
}

// ================== MFMA infra (fp16 2-way split, 3-product exact emulation) ==================
typedef _Float16 half8 __attribute__((ext_vector_type(8)));
typedef float f32x16 __attribute__((ext_vector_type(16)));
#define MFMA16(A,B,C) __builtin_amdgcn_mfma_f32_32x32x16_f16(A,B,C,0,0,0)

__device__ inline void gld16(const unsigned short* g, unsigned short* l){
    __builtin_amdgcn_global_load_lds((const __attribute__((address_space(1))) unsigned int*)g,
                                     (__attribute__((address_space(3))) unsigned int*)l, 16, 0, 0);
}
__device__ inline void split2w(const float* v, unsigned* hw, unsigned* lw){
#pragma unroll
    for(int u = 0; u < 4; ++u){
        _Float16 h0 = (_Float16)v[2*u];
        _Float16 l0 = (_Float16)(v[2*u] - (float)h0);
        _Float16 h1 = (_Float16)v[2*u+1];
        _Float16 l1 = (_Float16)(v[2*u+1] - (float)h1);
        hw[u] = (((unsigned)__builtin_bit_cast(unsigned short, h1)) << 16) | __builtin_bit_cast(unsigned short, h0);
        lw[u] = (((unsigned)__builtin_bit_cast(unsigned short, l1)) << 16) | __builtin_bit_cast(unsigned short, l0);
    }
}

// split kernel: xtok f32 [16384][512] -> SP[2][64][16384][8] fp16 bits
__global__ __launch_bounds__(256) void split2(const float* xt, unsigned short* SP){
    int e = blockIdx.x * 256 + threadIdx.x;   // 1,048,576 = 64 groups * 16384 rows
    int g = e >> 14, row = e & 16383;
    const float* src = xt + (size_t)row * 512 + g * 8;
    float4 a = *(const float4*)src;
    float4 b = *(const float4*)(src + 4);
    float v[8] = {a.x, a.y, a.z, a.w, b.x, b.y, b.z, b.w};
    unsigned hw[4], lw[4];
    split2w(v, hw, lw);
    *(uint4*)(void*)(SP + ((size_t)g * 16384 + row) * 8) = make_uint4(hw[0], hw[1], hw[2], hw[3]);
    *(uint4*)(void*)(SP + ((size_t)(64 + g) * 16384 + row) * 8) = make_uint4(lw[0], lw[1], lw[2], lw[3]);
}

// xmap f32 [4][64][64][256] -> XMS[2][32][4*66*66][8] f16 (zero-padded 66x66 grid)
__global__ __launch_bounds__(256) void split_xmap(const float* xmap, unsigned short* XMS){
    int e = blockIdx.x * 256 + threadIdx.x;      // 557,568 = 17424*32
    int g = e & 31, pix = e >> 5;
    int b = pix / 4356, r = pix - b * 4356;
    int py = r / 66, px = r - py * 66;
    float v[8];
    if(py >= 1 && py <= 64 && px >= 1 && px <= 64){
        const float* src = xmap + ((size_t)(b << 12) + ((py - 1) << 6) + (px - 1)) * 256 + g * 8;
        float4 a = *(const float4*)src;
        float4 c = *(const float4*)(src + 4);
        v[0]=a.x; v[1]=a.y; v[2]=a.z; v[3]=a.w; v[4]=c.x; v[5]=c.y; v[6]=c.z; v[7]=c.w;
    } else {
#pragma unroll
        for(int u = 0; u < 8; ++u) v[u] = 0.f;
    }
    unsigned hw[4], lw[4];
    split2w(v, hw, lw);
    *(uint4*)(void*)(XMS + ((size_t)g * 17424 + pix) * 8) = make_uint4(hw[0], hw[1], hw[2], hw[3]);
    *(uint4*)(void*)(XMS + ((size_t)(32 + g) * 17424 + pix) * 8) = make_uint4(lw[0], lw[1], lw[2], lw[3]);
}

// conv_w [2304][512] -> CWT[2][288][512][8] (k-transposed: row j holds its k-vector)
__global__ __launch_bounds__(256) void split_cw(const void* cwp, unsigned short* CWT, const int* mode){
    int m = GETM(mode);
    int e = blockIdx.x * 256 + threadIdx.x;   // 147,456 = 288*512
    int col = e & 511, kg = e >> 9;
    float v[8];
#pragma unroll
    for(int u = 0; u < 8; ++u) v[u] = ldin(cwp, (long)(kg * 8 + u) * 512 + col, m);
    unsigned hw[4], lw[4];
    split2w(v, hw, lw);
    *(uint4*)(void*)(CWT + ((size_t)kg * 512 + col) * 8) = make_uint4(hw[0], hw[1], hw[2], hw[3]);
    *(uint4*)(void*)(CWT + ((size_t)(288 + kg) * 512 + col) * 8) = make_uint4(lw[0], lw[1], lw[2], lw[3]);
}

// skip_w [256][512] -> SWT[2][32][512][8]
__global__ __launch_bounds__(256) void split_sw(const void* swp, unsigned short* SWT, const int* mode){
    int m = GETM(mode);
    int e = blockIdx.x * 256 + threadIdx.x;   // 16,384 = 32*512
    int col = e & 511, kg = e >> 9;
    float v[8];
#pragma unroll
    for(int u = 0; u < 8; ++u) v[u] = ldin(swp, (long)(kg * 8 + u) * 512 + col, m);
    unsigned hw[4], lw[4];
    split2w(v, hw, lw);
    *(uint4*)(void*)(SWT + ((size_t)kg * 512 + col) * 8) = make_uint4(hw[0], hw[1], hw[2], hw[3]);
    *(uint4*)(void*)(SWT + ((size_t)(32 + kg) * 512 + col) * 8) = make_uint4(lw[0], lw[1], lw[2], lw[3]);
}

// x (mode-typed) [16384][256] -> XS[2][32][16384][8]
__global__ __launch_bounds__(256) void split_x(const void* xp, unsigned short* XS, const int* mode){
    int m = GETM(mode);
    int e = blockIdx.x * 256 + threadIdx.x;   // 524,288 = 32*16384
    int g = e & 31, row = e >> 5;
    long base = (long)row * 256 + g * 8;
    float v[8];
#pragma unroll
    for(int u = 0; u < 8; ++u) v[u] = ldin(xp, base + u, m);
    unsigned hw[4], lw[4];
    split2w(v, hw, lw);
    *(uint4*)(void*)(XS + ((size_t)g * 16384 + row) * 8) = make_uint4(hw[0], hw[1], hw[2], hw[3]);
    *(uint4*)(void*)(XS + ((size_t)(32 + g) * 16384 + row) * 8) = make_uint4(lw[0], lw[1], lw[2], lw[3]);
}

// shared MFMA inner math for conv/skip: consumes 32KB tile [s][tile][gl][128row][8] via STV
#define MFMA_CORE(STV) \
    _Pragma("unroll") \
    for(int ks = 0; ks < 2; ++ks){ \
        int kg = (ks << 1) + kh; \
        half8 ah0 = (STV)[kg*128 + rb];        half8 ah1 = (STV)[kg*128 + rb + 32]; \
        half8 bh0 = (STV)[(4+kg)*128 + cbx];   half8 bh1 = (STV)[(4+kg)*128 + cbx + 32]; \
        half8 al0 = (STV)[(8+kg)*128 + rb];    half8 al1 = (STV)[(8+kg)*128 + rb + 32]; \
        half8 bl0 = (STV)[(12+kg)*128 + cbx];  half8 bl1 = (STV)[(12+kg)*128 + cbx + 32]; \
        acc00 = MFMA16(ah0,bh0,acc00); acc00 = MFMA16(ah0,bl0,acc00); acc00 = MFMA16(al0,bh0,acc00); \
        acc01 = MFMA16(ah0,bh1,acc01); acc01 = MFMA16(ah0,bl1,acc01); acc01 = MFMA16(al0,bh1,acc01); \
        acc10 = MFMA16(ah1,bh0,acc10); acc10 = MFMA16(ah1,bl0,acc10); acc10 = MFMA16(al1,bh0,acc10); \
        acc11 = MFMA16(ah1,bh1,acc11); acc11 = MFMA16(ah1,bl1,acc11); acc11 = MFMA16(al1,bh1,acc11); \
    }

#define MFMA_STEP { const half8* stv_ = (const half8*)stage; MFMA_CORE(stv_) }

// ---------- conv3x3 s2 p1 via im2col on MFMA: 128x128 tile, K-split x4, atomic epilogue ----------
__global__ __launch_bounds__(256) void conv_mfma(const unsigned short* XMS, const unsigned short* CWT,
                                                 float* C){
    __shared__ __align__(16) unsigned short stage[16384];
    int t = threadIdx.x;
    int j0 = blockIdx.x * 128;                // 4
    int i0 = blockIdx.y * 128;                // 32
    int kz = blockIdx.z;                      // 4 (K chunks of 576)
    int w = t >> 6, lane = t & 63, kh = lane >> 5;
    int row = t & 127, glo = t >> 7;
    int p = i0 + row;
    int b = p >> 10, r = p & 1023, oy = r >> 5, ox = r & 31;
    long pixbase = (long)b * 4356 + oy * 132 + ox * 2;
    long colv = (long)(j0 + row) * 8;
    f32x16 acc00, acc01, acc10, acc11;
#pragma unroll
    for(int q = 0; q < 16; ++q){ acc00[q]=0.f; acc01[q]=0.f; acc10[q]=0.f; acc11[q]=0.f; }
    unsigned short* ldsb = stage + (size_t)(t & 192) * 8;
    int rb = ((w >> 1) << 6) + (lane & 31);
    int cbx = ((w & 1) << 6) + (lane & 31);
    for(int c_ = 0; c_ < 18; ++c_){
        int cg = kz * 18 + c_;
        int tap = cg >> 3;                    // 0..8 (chunk of 32 stays within one tap)
        int tdiv = tap / 3;
        long toff = (long)tdiv * 66 + (tap - tdiv * 3);
        int c8 = (cg & 7) << 2;               // channel kgroup base
        long apix = (pixbase + toff) * 8;
        const unsigned short* a0 = XMS + (size_t)(c8 + glo)          * 139392 + apix;
        const unsigned short* a1 = XMS + (size_t)(c8 + 2 + glo)      * 139392 + apix;
        const unsigned short* a4 = XMS + (size_t)(32 + c8 + glo)     * 139392 + apix;
        const unsigned short* a5 = XMS + (size_t)(32 + c8 + 2 + glo) * 139392 + apix;
        const unsigned short* b2 = CWT + (size_t)((cg << 2) + glo)           * 4096 + colv;
        const unsigned short* b3 = CWT + (size_t)((cg << 2) + 2 + glo)       * 4096 + colv;
        const unsigned short* b6 = CWT + (size_t)(288 + (cg << 2) + glo)     * 4096 + colv;
        const unsigned short* b7 = CWT + (size_t)(288 + (cg << 2) + 2 + glo) * 4096 + colv;
        __syncthreads();
        gld16(a0, ldsb);          gld16(a1, ldsb + 2048);
        gld16(b2, ldsb + 4096);   gld16(b3, ldsb + 6144);
        gld16(a4, ldsb + 8192);   gld16(a5, ldsb + 10240);
        gld16(b6, ldsb + 12288);  gld16(b7, ldsb + 14336);
        __syncthreads();
        MFMA_STEP
    }
    int rbase = i0 + ((w >> 1) << 6);
    int cbase = j0 + ((w & 1) << 6) + (lane & 31);
#pragma unroll
    for(int q = 0; q < 16; ++q){
        int rL = (q & 3) + ((q >> 2) << 3) + (kh << 2);
        unsafeAtomicAdd(&C[(size_t)(rbase + rL) * 512 + cbase],           acc00[q]);
        unsafeAtomicAdd(&C[(size_t)(rbase + rL) * 512 + cbase + 32],      acc01[q]);
        unsafeAtomicAdd(&C[(size_t)(rbase + 32 + rL) * 512 + cbase],      acc10[q]);
        unsafeAtomicAdd(&C[(size_t)(rbase + 32 + rL) * 512 + cbase + 32], acc11[q]);
    }
}

// ---------- skip GEMM on MFMA: x[16384,256] @ skip_w -> xtok (direct store) ----------
__global__ __launch_bounds__(256) void skip_mfma(const unsigned short* XS, const unsigned short* SWT,
                                                 float* C){
    __shared__ __align__(16) unsigned short stage[16384];
    int t = threadIdx.x;
    int j0 = blockIdx.x * 128;                // 4
    int i0 = blockIdx.y * 128;                // 128
    int w = t >> 6, lane = t & 63, kh = lane >> 5;
    int row = t & 127, glo = t >> 7;
    long arow = (long)(i0 + row) * 8;
    long colv = (long)(j0 + row) * 8;
    f32x16 acc00, acc01, acc10, acc11;
#pragma unroll
    for(int q = 0; q < 16; ++q){ acc00[q]=0.f; acc01[q]=0.f; acc10[q]=0.f; acc11[q]=0.f; }
    unsigned short* ldsb = stage + (size_t)(t & 192) * 8;
    int rb = ((w >> 1) << 6) + (lane & 31);
    int cbx = ((w & 1) << 6) + (lane & 31);
    for(int c_ = 0; c_ < 8; ++c_){
        const unsigned short* a0 = XS + (size_t)((c_ << 2) + glo)          * 131072 + arow;
        const unsigned short* a1 = XS + (size_t)((c_ << 2) + 2 + glo)      * 131072 + arow;
        const unsigned short* a4 = XS + (size_t)(32 + (c_ << 2) + glo)     * 131072 + arow;
        const unsigned short* a5 = XS + (size_t)(32 + (c_ << 2) + 2 + glo) * 131072 + arow;
        const unsigned short* b2 = SWT + (size_t)((c_ << 2) + glo)          * 4096 + colv;
        const unsigned short* b3 = SWT + (size_t)((c_ << 2) + 2 + glo)      * 4096 + colv;
        const unsigned short* b6 = SWT + (size_t)(32 + (c_ << 2) + glo)     * 4096 + colv;
        const unsigned short* b7 = SWT + (size_t)(32 + (c_ << 2) + 2 + glo) * 4096 + colv;
        __syncthreads();
        gld16(a0, ldsb);          gld16(a1, ldsb + 2048);
        gld16(b2, ldsb + 4096);   gld16(b3, ldsb + 6144);
        gld16(a4, ldsb + 8192);   gld16(a5, ldsb + 10240);
        gld16(b6, ldsb + 12288);  gld16(b7, ldsb + 14336);
        __syncthreads();
        MFMA_STEP
    }
    int rbase = i0 + ((w >> 1) << 6);
    int cbase = j0 + ((w & 1) << 6) + (lane & 31);
#pragma unroll
    for(int q = 0; q < 16; ++q){
        int rL = (q & 3) + ((q >> 2) << 3) + (kh << 2);
        C[(size_t)(rbase + rL) * 512 + cbase]           = acc00[q];
        C[(size_t)(rbase + rL) * 512 + cbase + 32]      = acc01[q];
        C[(size_t)(rbase + 32 + rL) * 512 + cbase]      = acc10[q];
        C[(size_t)(rbase + 32 + rL) * 512 + cbase + 32] = acc11[q];
    }
}

// ---------- map2token ----------
__global__ void wsum_add(const int* idx_agg, const void* aggw, float* wsum, const int* mode){
    int m = GETM(mode);
    int e = blockIdx.x * 256 + threadIdx.x;   // 16384
    int b = e >> 12;
    unsafeAtomicAdd(&wsum[(b << 12) + (idx_agg[e] & 4095)], ldin(aggw, e, m));
}

__global__ __launch_bounds__(128) void scatter_tok(const void* loc, const int* idx_agg,
                                                   const void* aggw, const float* convo,
                                                   const float* wsum, float* xtok, const int* mode){
    int m = GETM(mode);
    int bn = blockIdx.x;
    int b = bn >> 12;
    float lx = ldin(loc, (long)bn * 2 + 0, m);
    float ly = ldin(loc, (long)bn * 2 + 1, m);
    int p = pix_idx(lx, ly, 16.f, 32);
    int tk = idx_agg[bn] & 4095;
    float w = ldin(aggw, bn, m);
    float scale = w / wsum[(b << 12) + tk];
    const float* pv = convo + ((size_t)(b << 10) + p) * 512;
    float* dst = xtok + ((size_t)(b << 12) + tk) * 512;
    int c = threadIdx.x * 4;
    float4 v = *(const float4*)&pv[c];
    unsafeAtomicAdd(&dst[c + 0], v.x * scale);
    unsafeAtomicAdd(&dst[c + 1], v.y * scale);
    unsafeAtomicAdd(&dst[c + 2], v.z * scale);
    unsafeAtomicAdd(&dst[c + 3], v.w * scale);
}

// ---------- fused layernorm + conf + weight + x2 ----------
__global__ __launch_bounds__(128) void ln_conf(float* xtok, const void* g_, const void* b_,
                                               const void* cw_, const void* cb_,
                                               float* wgt, float* x2a, const int* mode){
    int m = GETM(mode);
    int row = blockIdx.x;        // 0..16383
    int t = threadIdx.x;         // 128
    float* xr = xtok + (size_t)row * 512;
    int c0 = t * 4;
    float4 v = *(const float4*)&xr[c0];
    float xv[4] = {v.x, v.y, v.z, v.w};
    __shared__ float red[2];
    __shared__ float red2[4];
    float s = xv[0] + xv[1] + xv[2] + xv[3];
    s = wred_add(s);
    if((t & 63) == 0) red[t >> 6] = s;
    __syncthreads();
    float mean = (red[0] + red[1]) * (1.f / 512.f);
    __syncthreads();
    float xc[4];
#pragma unroll
    for(int u = 0; u < 4; ++u) xc[u] = xv[u] - mean;
    float q = xc[0]*xc[0] + xc[1]*xc[1] + xc[2]*xc[2] + xc[3]*xc[3];
    q = wred_add(q);
    if((t & 63) == 0) red[t >> 6] = q;
    __syncthreads();
    float var = (red[0] + red[1]) * (1.f / 512.f);
    float rs = 1.0f / sqrtf(var + 1e-5f);
    float y[4];
#pragma unroll
    for(int u = 0; u < 4; ++u)
        y[u] = xc[u] * rs * ldin(g_, c0 + u, m) + ldin(b_, c0 + u, m);
    float4 st; st.x = y[0]; st.y = y[1]; st.z = y[2]; st.w = y[3];
    *(float4*)&xr[c0] = st;
    float cf = y[0]*ldin(cw_, c0+0, m) + y[1]*ldin(cw_, c0+1, m)
             + y[2]*ldin(cw_, c0+2, m) + y[3]*ldin(cw_, c0+3, m);
    float qq = y[0]*y[0] + y[1]*y[1] + y[2]*y[2] + y[3]*y[3];
    cf = wred_add(cf);
    qq = wred_add(qq);
    if((t & 63) == 0){ red2[t >> 6] = cf; red2[2 + (t >> 6)] = qq; }
    __syncthreads();
    if(t == 0){
        wgt[row] = expf(red2[0] + red2[1] + ldin(cb_, 0, m));
        x2a[row] = red2[2] + red2[3];
    }
}

// ================== 8-wave Gram core: 512 threads, BK=64 single buffer (8 rounds) ============
// Same 64KB LDS as the dbuf variant (2 blocks/CU, 16 waves — measured), but used as ONE
// 64KB stage holding TWO K-chunks per round: barrier-drain events halve (32 -> 16) and
// 8 loads/thread are in flight per drain instead of 4. Chunk order (2r, 2r+1) and per-chunk
// MFMA sequence unchanged -> bit-identical d2.
#define INITP8(R, AEXPR) const unsigned short* p##R; { \
    int cell = t + ((R) << 9); int row = cell & 127; int gl = (cell >> 7) & 3; \
    int tile = (cell >> 9) & 1; int sp_ = cell >> 10; \
    int grow = (z << 12) + (tile ? (j0 + row) : (AEXPR)); \
    p##R = SP + (size_t)((sp_ << 6) + gl) * 131072 + (size_t)grow * 8; }

#define GRAM8_CORE(AEXPR) \
    int w = t >> 6; int lane = t & 63; int kh = lane >> 5; \
    int ra = ((w & 3) << 5) + (lane & 31); \
    int cb = ((w >> 2) << 6) + (lane & 31); \
    f32x16 acc0, acc1; \
    _Pragma("unroll") for(int q_ = 0; q_ < 16; ++q_){ acc0[q_]=0.f; acc1[q_]=0.f; } \
    INITP8(0, AEXPR) INITP8(1, AEXPR) INITP8(2, AEXPR) INITP8(3, AEXPR) \
    { \
        unsigned short* ldsb = stage + (size_t)(t & 448) * 8; \
        for(int r_ = 0; r_ < 8; ++r_){ \
            __syncthreads(); \
            gld16(p0, ldsb);                  gld16(p1, ldsb + 4096); \
            gld16(p2, ldsb + 8192);           gld16(p3, ldsb + 12288); \
            gld16(p0 + 524288, ldsb + 16384); gld16(p1 + 524288, ldsb + 20480); \
            gld16(p2 + 524288, ldsb + 24576); gld16(p3 + 524288, ldsb + 28672); \
            p0 += 1048576; p1 += 1048576; p2 += 1048576; p3 += 1048576; \
            __syncthreads(); \
            _Pragma("unroll") \
            for(int h_ = 0; h_ < 2; ++h_){ \
                const half8* stv = (const half8*)(stage + (h_ << 14)); \
                _Pragma("unroll") \
                for(int ks = 0; ks < 2; ++ks){ \
                    int kg = (ks << 1) + kh; \
                    half8 ah  = stv[kg*128 + ra]; \
                    half8 al  = stv[(8+kg)*128 + ra]; \
                    half8 bh0 = stv[(4+kg)*128 + cb];   half8 bh1 = stv[(4+kg)*128 + cb + 32]; \
                    half8 bl0 = stv[(12+kg)*128 + cb];  half8 bl1 = stv[(12+kg)*128 + cb + 32]; \
                    acc0 = MFMA16(ah,bh0,acc0); acc0 = MFMA16(ah,bl0,acc0); acc0 = MFMA16(al,bh0,acc0); \
                    acc1 = MFMA16(ah,bh1,acc1); acc1 = MFMA16(ah,bl1,acc1); acc1 = MFMA16(al,bh1,acc1); \
                } \
            } \
        } \
    }

// dump the wave's two 32x32 quadrants into the 64x128 f32 window when its row-block is in phase
#define DUMP_ONE8(ACC, N) { \
    int coln = ((w >> 2) << 6) + ((N) << 5) + (lane & 31); \
    float xc2v = x2c[coln]; \
    _Pragma("unroll") for(int q = 0; q < 16; ++q){ \
        int rLw = (((w & 3) & 1) << 5) + (q & 3) + ((q >> 2) << 3) + (kh << 2); \
        d2t[rLw * 128 + coln] = x2r[(ph << 6) + rLw] + xc2v - 2.0f * ACC[q]; } }

#define DUMP8 if(((w & 3) >> 1) == ph){ DUMP_ONE8(acc0,0) DUMP_ONE8(acc1,1) }

// 5-list bitonic merge step via shfl_xor (lists sorted ascending; keeps 5 smallest)
#define MERGE5(B5, MK) { \
    float o0=__shfl_xor(B5[0],MK), o1=__shfl_xor(B5[1],MK), o2=__shfl_xor(B5[2],MK), \
          o3=__shfl_xor(B5[3],MK), o4=__shfl_xor(B5[4],MK); \
    B5[0]=fminf(B5[0],o4); B5[1]=fminf(B5[1],o3); B5[2]=fminf(B5[2],o2); \
    B5[3]=fminf(B5[3],o1); B5[4]=fminf(B5[4],o0); \
    sort5n(B5); }

// triangular block map: q -> (bi <= bj)
#define TRI_MAP(q, bi, bj)                                         \
    int bj = (int)((sqrtf(8.0f * (q) + 1.0f) - 1.0f) * 0.5f);      \
    while((bj + 1) * (bj + 2) / 2 <= (q)) bj++;                    \
    while(bj * (bj + 1) / 2 > (q)) bj--;                           \
    int bi = (q) - bj * (bj + 1) / 2;

// ---------- Pass A: top5 + max per row/col ----------
__global__ __launch_bounds__(512, 2) void gramA9(const unsigned short* SP, const float* x2b,
                                                 float* part5, float* pmax){
    __shared__ __align__(16) unsigned short stage[32768];   // 64KB stage; front aliased as d2
    __shared__ float x2r[128], x2c[128];
    float* d2t = (float*)stage;
    int z = blockIdx.z;
    TRI_MAP((int)blockIdx.x, bi, bj)
    int i0 = bi * 128, j0 = bj * 128;
    int t = threadIdx.x;
    if(t < 128) x2r[t] = x2b[(z << 12) + i0 + t];
    else if(t < 256) x2c[t - 128] = x2b[(z << 12) + j0 + (t - 128)];
    GRAM8_CORE(i0 + row)
    float c5[5] = {FLTMAX, FLTMAX, FLTMAX, FLTMAX, FLTMAX};
    float cmx = -FLTMAX;
    int colc = t >> 2, rhc = t & 3;
    for(int ph = 0; ph < 2; ++ph){
        __syncthreads();
        DUMP8
        __syncthreads();
        {   // row scan: 8 threads/row, 16 staggered cols each; 3-level shfl bitonic merge
            int rr = t >> 3, ch = t & 7;
            float b5[5] = {FLTMAX, FLTMAX, FLTMAX, FLTMAX, FLTMAX};
            float mx = -FLTMAX;
#pragma unroll
            for(int c = 0; c < 16; ++c){
                int col = (ch << 4) + ((rr + c) & 15);
                float v = d2t[rr * 128 + col];
                ins5(b5, v); mx = fmaxf(mx, v);
            }
#pragma unroll
            for(int lvl = 0; lvl < 3; ++lvl){
                int mk = 1 << lvl;
                MERGE5(b5, mk)
                mx = fmaxf(mx, __shfl_xor(mx, mk));
            }
            if(ch == 0){
                size_t rowg = (size_t)(z << 12) + i0 + (ph << 6) + rr;
                size_t o = (rowg * 32 + bj) * 5;
                part5[o]=b5[0]; part5[o+1]=b5[1]; part5[o+2]=b5[2]; part5[o+3]=b5[3]; part5[o+4]=b5[4];
                pmax[rowg * 32 + bj] = mx;
            }
        }
        if(bi != bj){   // col accumulate: 4 threads/col, 16 rows each per phase
#pragma unroll
            for(int r2 = 0; r2 < 16; ++r2){
                float v = d2t[(((rhc << 4) + r2) << 7) + colc];
                ins5(c5, v); cmx = fmaxf(cmx, v);
            }
        }
    }
    if(bi != bj){
#pragma unroll
        for(int lvl = 0; lvl < 2; ++lvl){
            int mk = 1 << lvl;
            MERGE5(c5, mk)
            cmx = fmaxf(cmx, __shfl_xor(cmx, mk));
        }
        if(rhc == 0){
            size_t rowg = (size_t)(z << 12) + j0 + colc;
            size_t o = (rowg * 32 + bi) * 5;
            part5[o]=c5[0]; part5[o+1]=c5[1]; part5[o+2]=c5[2]; part5[o+3]=c5[3]; part5[o+4]=c5[4];
            pmax[rowg * 32 + bi] = cmx;
        }
    }
}

// ---------- reduceA4: wave-parallel bitonic top5 merge; NO atomics (block max -> bmax) ----------
__global__ __launch_bounds__(256) void reduceA4(const float* part5, const float* pmax,
                                                float* dens_b, float* bmax){
    __shared__ float wmx[4];
    int t = threadIdx.x;
    int wv = t >> 6, lane = t & 63;
    int bi = blockIdx.x * 4 + wv;             // token 0..16383, grid 4096 (block within one batch)
    int l = lane & 31;                        // both 32-halves compute identically
    const float* p = part5 + ((size_t)bi * 32 + l) * 5;
    float a[5] = {p[0], p[1], p[2], p[3], p[4]};
    float mm = pmax[(size_t)bi * 32 + l];
#pragma unroll
    for(int lvl = 0; lvl < 5; ++lvl){
        int mask = 1 << lvl;
        MERGE5(a, mask)
        mm = fmaxf(mm, __shfl_xor(mm, mask));
    }
    if(lane == 0){
        const float sqrtC = 22.627416997969522f;
        float s = 0.f;
#pragma unroll
        for(int q = 0; q < 5; ++q){
            float d = sqrtf(fmaxf(a[q], 0.f)) / sqrtC;
            s = s + d * d;
        }
        dens_b[bi] = expf(-(s / 5.0f));
        wmx[wv] = mm;
    }
    __syncthreads();
    if(t == 0)
        bmax[blockIdx.x] = fmaxf(fmaxf(fmaxf(wmx[0], wmx[1]), fmaxf(wmx[2], wmx[3])), 0.f);
}

// per-batch dmax: reduce 1024 block maxes -> dmaxf[z] (written as float; reduceB3 reads bits)
__global__ __launch_bounds__(256) void dmax_k(const float* bmax, float* dmaxf){
    __shared__ float sm[4];
    int z = blockIdx.x, t = threadIdx.x;
    const float* src = bmax + (z << 10);
    float m = fmaxf(fmaxf(src[t], src[t + 256]), fmaxf(src[t + 512], src[t + 768]));
    for(int o = 32; o > 0; o >>= 1) m = fmaxf(m, __shfl_down(m, o));
    if((t & 63) == 0) sm[t >> 6] = m;
    __syncthreads();
    if(t == 0) dmaxf[z] = fmaxf(fmaxf(sm[0], sm[1]), fmaxf(sm[2], sm[3]));
}

// ---------- Pass B: min dist to any higher-density token ----------
__global__ __launch_bounds__(512, 2) void gramB9(const unsigned short* SP, const float* x2b,
                                                 const float* dens_b, float* pmin){
    __shared__ __align__(16) unsigned short stage[32768];
    __shared__ float x2r[128], x2c[128], densr[128], densc[128];
    float* d2t = (float*)stage;
    int z = blockIdx.z;
    TRI_MAP((int)blockIdx.x, bi, bj)
    int i0 = bi * 128, j0 = bj * 128;
    int t = threadIdx.x;
    if(t < 128){ x2r[t] = x2b[(z << 12) + i0 + t]; densr[t] = dens_b[(z << 12) + i0 + t]; }
    else if(t < 256){ x2c[t-128] = x2b[(z << 12) + j0 + (t-128)]; densc[t-128] = dens_b[(z << 12) + j0 + (t-128)]; }
    GRAM8_CORE(i0 + row)
    float colmin = FLTMAX;
    int colc = t >> 2, rhc = t & 3;
    float dcc = 0.f;
    for(int ph = 0; ph < 2; ++ph){
        __syncthreads();
        DUMP8
        __syncthreads();
        {
            int rr = t >> 3, ch = t & 7;
            float dr = densr[(ph << 6) + rr];
            float pm = FLTMAX;
#pragma unroll
            for(int c = 0; c < 16; ++c){
                int col = (ch << 4) + ((rr + c) & 15);
                float v = d2t[rr * 128 + col];
                if(densc[col] > dr) pm = fminf(pm, v);
            }
#pragma unroll
            for(int lvl = 0; lvl < 3; ++lvl) pm = fminf(pm, __shfl_xor(pm, 1 << lvl));
            if(ch == 0) pmin[((size_t)(z << 12) + i0 + (ph << 6) + rr) * 32 + bj] = pm;
        }
        if(bi != bj){
            dcc = densc[colc];
#pragma unroll
            for(int r2 = 0; r2 < 16; ++r2){
                int rLw = (rhc << 4) + r2;
                float v = d2t[(rLw << 7) + colc];
                if(densr[(ph << 6) + rLw] > dcc) colmin = fminf(colmin, v);
            }
        }
    }
    if(bi != bj){
        colmin = fminf(colmin, __shfl_xor(colmin, 1));
        colmin = fminf(colmin, __shfl_xor(colmin, 2));
        if(rhc == 0) pmin[((size_t)(z << 12) + j0 + colc) * 32 + bi] = colmin;
    }
}

// flat: one thread per token (same fminf chain order as before -> bit-identical)
__global__ __launch_bounds__(256) void reduceB3(const float* pmin, const float* dens_b,
                                                const int* dmax_b, float* score_b){
    int bi = blockIdx.x * 256 + threadIdx.x;  // 0..16383
    float m = FLTMAX;
    for(int c = 0; c < 32; ++c) m = fminf(m, pmin[(size_t)bi * 32 + c]);
    const float sqrtC = 22.627416997969522f;
    float dp;
    if(m == FLTMAX) dp = sqrtf(fmaxf(__int_as_float(dmax_b[bi >> 12]), 0.f)) / sqrtC;
    else            dp = sqrtf(fmaxf(m, 0.f)) / sqrtC;
    score_b[bi] = dp * dens_b[bi];
}

// ---------- Pass C: gathered-center Gram -> per-(token, centerblock) argmin ----------
__global__ __launch_bounds__(512, 2) void gramC9(const unsigned short* SP, const float* x2b,
                                                 const int* idown_b, float* pcd, int* pci){
    __shared__ __align__(16) unsigned short stage[32768];
    __shared__ float x2r[128], x2c[128];
    __shared__ int idzl[128];
    float* d2t = (float*)stage;
    int z = blockIdx.z;
    int s0 = blockIdx.y * 128, j0 = blockIdx.x * 128;
    int t = threadIdx.x;
    if(t < 128) idzl[t] = idown_b[(z << 10) + s0 + t];
    else if(t < 256) x2c[t - 128] = x2b[(z << 12) + j0 + (t - 128)];
    __syncthreads();
    if(t < 128) x2r[t] = x2b[(z << 12) + idzl[t]];
    GRAM8_CORE(idzl[row])
    const float sqrtC = 22.627416997969522f;
    float bd = FLTMAX; int bsi = 0;
    int colc = t >> 2, rhc = t & 3;
    for(int ph = 0; ph < 2; ++ph){
        __syncthreads();
        DUMP8
        __syncthreads();
#pragma unroll
        for(int r2 = 0; r2 < 16; ++r2){          // rows ascend globally across phases
            int rLw = (rhc << 4) + r2;
            float d2v = d2t[(rLw << 7) + colc];
            float d = sqrtf(fmaxf(d2v, 0.f)) / sqrtC;
            if(d < bd){ bd = d; bsi = (ph << 6) + rLw; }
        }
    }
#pragma unroll
    for(int lvl = 0; lvl < 2; ++lvl){            // merge rhc 0..3; tie -> smaller center row
        int mk = 1 << lvl;
        float od = __shfl_xor(bd, mk);
        int   oi = __shfl_xor(bsi, mk);
        if(od < bd || (od == bd && oi < bsi)){ bd = od; bsi = oi; }
    }
    if(rhc == 0){
        pcd[((size_t)(z << 12) + j0 + colc) * 8 + blockIdx.y] = bd;
        pci[((size_t)(z << 12) + j0 + colc) * 8 + blockIdx.y] = s0 + bsi;
    }
}

__global__ void reduceC2(const float* pcd, const int* pci, int* iclus_b){
    int jg = blockIdx.x * 256 + threadIdx.x;      // 0..16383
    float bd = FLTMAX;
    int bs = 0;
    for(int c = 0; c < 8; ++c){
        float d = pcd[(size_t)jg * 8 + c];
        if(d < bd){ bd = d; bs = pci[(size_t)jg * 8 + c]; }
    }
    iclus_b[jg] = bs;
}

// ---------- bitonic sort (score desc, idx asc) -> top 1024; blockIdx.x = batch ----------
__global__ __launch_bounds__(1024) void sort_topk(const float* score, int* idown){
    __shared__ float ss[4096];
    __shared__ int sid[4096];
    int t = threadIdx.x;
    const float* sc = score + (size_t)blockIdx.x * 4096;
    int* id = idown + (size_t)blockIdx.x * 1024;
    for(int v = t; v < 4096; v += 1024){ ss[v] = sc[v]; sid[v] = v; }
    __syncthreads();
    for(int k = 2; k <= 4096; k <<= 1){
        for(int j = k >> 1; j > 0; j >>= 1){
            for(int v = t; v < 4096; v += 1024){
                int l = v ^ j;
                if(l > v){
                    float sv = ss[v], sl = ss[l];
                    int iv = sid[v], il = sid[l];
                    bool before_lv = (sl > sv) || (sl == sv && il < iv);
                    bool before_vl = (sv > sl) || (sv == sl && iv < il);
                    bool asc = ((v & k) == 0);
                    bool sw = asc ? before_lv : before_vl;
                    if(sw){ ss[v] = sl; ss[l] = sv; sid[v] = il; sid[l] = iv; }
                }
            }
            __syncthreads();
        }
    }
    for(int v = t; v < 1024; v += 1024) id[v] = sid[v];
}

// ---------- merge tokens + outputs (FLOAT32 out) ----------
__global__ void allw_add(const int* iclus, const float* wgt, float* allw){
    int e = blockIdx.x * 256 + threadIdx.x;   // 16384
    int b = e >> 12;
    unsafeAtomicAdd(&allw[(b << 10) + (iclus[e] & 1023)], wgt[e]);
}
__global__ void norm_k(const int* iclus, const float* wgt, const float* allw, float* nw){
    int e = blockIdx.x * 256 + threadIdx.x;
    int b = e >> 12;
    nw[e] = wgt[e] / allw[(b << 10) + (iclus[e] & 1023)];
}
// abuf + per-batch max weight; block-uniform batch -> ONE atomicMax per block
__global__ __launch_bounds__(256) void abuf_k2(const int* idx_agg, const void* aggw, const float* nw,
                                               float* abuf, float* maxw, const int* mode){
    __shared__ float wmx[4];
    int m = GETM(mode);
    int t = threadIdx.x;
    int e = blockIdx.x * 256 + t;
    int b = e >> 12;                          // uniform within block (256 | 4096)
    float a = ldin(aggw, e, m) * nw[(b << 12) + (idx_agg[e] & 4095)];
    abuf[e] = a;
    float mm = a;
    for(int o = 32; o > 0; o >>= 1) mm = fmaxf(mm, __shfl_down(mm, o));
    if((t & 63) == 0) wmx[t >> 6] = mm;
    __syncthreads();
    if(t == 0){
        float bm = fmaxf(fmaxf(wmx[0], wmx[1]), fmaxf(wmx[2], wmx[3]));
        atomicMax((int*)&maxw[b], __float_as_int(bm));
    }
}
__global__ __launch_bounds__(128) void scatter_xdown(const int* iclus, const float* nw,
                                                     const float* xtok, float* xdown){
    int bn = blockIdx.x;           // 0..16383
    int b = bn >> 12;
    int cl = iclus[bn] & 1023;
    float w = nw[bn];
    const float* src = xtok + (size_t)bn * 512;
    float* dst = xdown + ((size_t)(b << 10) + cl) * 512;
    int c = threadIdx.x * 4;
    float4 v = *(const float4*)&src[c];
    unsafeAtomicAdd(&dst[c + 0], v.x * w);
    unsafeAtomicAdd(&dst[c + 1], v.y * w);
    unsafeAtomicAdd(&dst[c + 2], v.z * w);
    unsafeAtomicAdd(&dst[c + 3], v.w * w);
}

__global__ void out0_k(const float* xdown, float* out){
    int e = blockIdx.x * 256 + threadIdx.x;
    if(e < 2097152) out[e] = xdown[e];
}
// fused out1 + out2 (both 16384-elem)
__global__ void out12_k(const int* idx_agg, const int* iclus, const float* abuf,
                        const float* maxw, float* out){
    int e = blockIdx.x * 256 + threadIdx.x;   // 16384
    int b = e >> 12;
    int ic = iclus[(b << 12) + (idx_agg[e] & 4095)];
    out[2097152 + e] = (float)ic;
    out[2097152 + 16384 + e] = abuf[e] / maxw[b];
}

// ---------- launch ----------
extern "C" void kernel_launch(void* const* d_in, const int* in_sizes, int n_in,
                              void* d_out, int out_size, void* d_ws, size_t ws_size,
                              hipStream_t stream){
    (void)in_sizes; (void)n_in; (void)out_size; (void)ws_size;
    const void* x    = d_in[0];
    const void* loc  = d_in[1];
    const int* idx_agg = (const int*)d_in[2];
    const void* aggw = d_in[3];
    const void* cw   = d_in[7];
    const void* cb   = d_in[8];
    const void* sw   = d_in[9];
    const void* lg   = d_in[10];
    const void* lnb  = d_in[11];
    const void* cfw  = d_in[12];
    const void* cfb  = d_in[13];
    float* out = (float*)d_out;

    // Phase-aliased layout, total 21,258,249 floats = 85.0 MB (ws >= 101 MB proven).
    float* ws    = (float*)d_ws;
    float* xtok  = ws;                        // 8,388,608
    float* xmap  = ws + 8388608;              // 4,194,304
    float* convo = ws + 12582912;             // 2,097,152
    float* xdown = ws + 14680064;             // 2,097,152
    unsigned short* SP  = (unsigned short*)(ws + 8388608);    // 16,777,216 shorts
    unsigned short* CWT = (unsigned short*)(ws + 14680064);   // 2,359,296 shorts
    unsigned short* SWT = (unsigned short*)(ws + 15859712);   // 262,144 shorts
    unsigned short* XMS = (unsigned short*)(ws + 16777216);   // 8,921,088 shorts
    unsigned short* XS  = (unsigned short*)(ws + 16777216);   // 8,388,608 shorts
    float* cnt   = ws + 16777216;             // 16,384 (phase 1; reused as bmax[4096] in clustering)
    float* part5 = ws + 16793600;             // 2,621,440
    float* pmaxb = ws + 19415040;             // 524,288
    float* pminb = ws + 19939328;             // 524,288
    float* pcd   = ws + 20463616;             // 131,072
    int*   pci   = (int*)(ws + 20594688);     // 131,072
    float* x2    = ws + 20725760;             // 16,384
    float* wgt   = ws + 20742144;             // 16,384
    float* dens  = ws + 20758528;             // 16,384
    float* score = ws + 20774912;             // 16,384
    float* wsum  = ws + 20791296;             // 16,384
    float* allw  = ws + 20807680;             // 4,096 (adjacent to wsum)
    float* nw    = ws + 20811776;             // 16,384
    float* dmaxf = ws + 21237760;             // 4
    float* maxw  = ws + 21237764;             // 4
    int*   idown = (int*)(ws + 21237768);     // 4,096
    int*   iclus = (int*)(ws + 21241864);     // 16,384
    int*   mode  = (int*)(ws + 21258248);     // 1 (hit count)

    hipMemsetAsync(mode, 0, 4, stream);
    detect_mode<<<64, 256, 0, stream>>>(x, mode);

    hipMemsetAsync(xmap, 0, (size_t)4194304 * 4, stream);
    hipMemsetAsync(cnt, 0, (size_t)16384 * 4, stream);
    hipMemsetAsync(dmaxf, 0, 8 * 4, stream);                         // dmax[4] + maxw[4]

    scatter_map<<<16384, 256, 0, stream>>>(x, loc, idx_agg, xmap, cnt, mode);
    divide_map<<<16384, 256, 0, stream>>>(xmap, cnt, 4194304);

    // conv on MFMA
    split_xmap<<<2178, 256, 0, stream>>>(xmap, XMS);
    split_cw<<<576, 256, 0, stream>>>(cw, CWT, mode);
    init_convo<<<8192, 256, 0, stream>>>(convo, cb, mode);
    conv_mfma<<<dim3(4, 32, 4), 256, 0, stream>>>(XMS, CWT, convo);

    // skip GEMM on MFMA (XS reuses XMS region -> after conv_mfma)
    split_x<<<2048, 256, 0, stream>>>(x, XS, mode);
    split_sw<<<64, 256, 0, stream>>>(sw, SWT, mode);
    skip_mfma<<<dim3(4, 128), 256, 0, stream>>>(XS, SWT, xtok);

    fill_f32<<<80, 256, 0, stream>>>(wsum, 1e-6f, 20480);            // wsum + allw (adjacent)
    wsum_add<<<64, 256, 0, stream>>>(idx_agg, aggw, wsum, mode);
    scatter_tok<<<16384, 128, 0, stream>>>(loc, idx_agg, aggw, convo, wsum, xtok, mode);
    ln_conf<<<16384, 128, 0, stream>>>(xtok, lg, lnb, cfw, cfb, wgt, x2, mode);

    // ---- clustering: fp16-split MFMA Gram, 8-wave BK=64 blocks; atomic-free reductions ----
    split2<<<4096, 256, 0, stream>>>(xtok, SP);
    gramA9<<<dim3(528, 1, 4), 512, 0, stream>>>(SP, x2, part5, pmaxb);
    reduceA4<<<4096, 256, 0, stream>>>(part5, pmaxb, dens, cnt);     // cnt reused as bmax[4096]
    dmax_k<<<4, 256, 0, stream>>>(cnt, dmaxf);
    gramB9<<<dim3(528, 1, 4), 512, 0, stream>>>(SP, x2, dens, pminb);
    reduceB3<<<64, 256, 0, stream>>>(pminb, dens, (int*)dmaxf, score);
    sort_topk<<<4, 1024, 0, stream>>>(score, idown);
    gramC9<<<dim3(32, 8, 4), 512, 0, stream>>>(SP, x2, idown, pcd, pci);
    reduceC2<<<64, 256, 0, stream>>>(pcd, pci, iclus);

    hipMemsetAsync(xdown, 0, (size_t)2097152 * 4, stream);           // SP/CWT/SWT dead now

    allw_add<<<64, 256, 0, stream>>>(iclus, wgt, allw);
    norm_k<<<64, 256, 0, stream>>>(iclus, wgt, allw, nw);
    abuf_k2<<<64, 256, 0, stream>>>(idx_agg, aggw, nw, score, maxw, mode);  // score reused as abuf

    scatter_xdown<<<16384, 128, 0, stream>>>(iclus, nw, xtok, xdown);

    out0_k<<<8192, 256, 0, stream>>>(xdown, out);
    out12_k<<<64, 256, 0, stream>>>(idx_agg, iclus, score, maxw, out);
}

// Round 13
// 973.455 us; speedup vs baseline: 1.0417x; 1.0417x over previous
//
#include <hip/hip_runtime.h>

#define FLTMAX 3.402823466e+38f

// ---------- helpers ----------
__device__ inline float b2f(unsigned short u){
    return __uint_as_float(((unsigned int)u) << 16);
}
// flag-dispatched input load: mode=1 -> f32 buffer, mode=0 -> bf16 buffer
__device__ inline float ldin(const void* p, long i, int f32m){
    return f32m ? ((const float*)p)[i] : b2f(((const unsigned short*)p)[i]);
}
__device__ inline int pix_idx(float lx, float ly, float half_, int wh){
    lx = fminf(fmaxf(lx, -1.f), 1.f);
    ly = fminf(fmaxf(ly, -1.f), 1.f);
    int px = (int)rintf((lx + 1.f) * half_ - 0.5f);   // round-half-even = jnp.round
    int py = (int)rintf((ly + 1.f) * half_ - 0.5f);
    px = min(max(px, 0), wh - 1);
    py = min(max(py, 0), wh - 1);
    return py * wh + px;
}
__device__ inline void ins5(float* b5, float d){
    if(d < b5[4]){
        b5[4] = d;
#pragma unroll
        for(int q = 4; q > 0; --q){
            if(b5[q] < b5[q-1]){ float tm = b5[q]; b5[q] = b5[q-1]; b5[q-1] = tm; }
        }
    }
}
// full 5-element sorting network (9 comparators) — sorts ANY order, branchless
__device__ inline void sort5n(float* a){
#define CMPX(i,j){ float lo_=fminf(a[i],a[j]); float hi_=fmaxf(a[i],a[j]); a[i]=lo_; a[j]=hi_; }
    CMPX(0,1) CMPX(3,4) CMPX(2,4) CMPX(2,3) CMPX(0,3) CMPX(0,2) CMPX(1,4) CMPX(1,3) CMPX(1,2)
#undef CMPX
}
__device__ inline float wred_add(float v){
    for(int o = 32; o > 0; o >>= 1) v += __shfl_down(v, o);
    return v;
}

// ---------- dtype auto-detect (64 blocks, atomic count; mode[0] = hit count) ----------
__global__ __launch_bounds__(256) void detect_mode(const void* xraw, int* flag){
    __shared__ int sh[256];
    const unsigned short* p = (const unsigned short*)xraw;
    int t = threadIdx.x, c = 0;
    int base = blockIdx.x * 1024;
    for(int i = base + t; i < base + 1024; i += 256){
        float v = b2f(p[i]);
        if(!(fabsf(v) < 100.f)) c++;
    }
    sh[t] = c;
    __syncthreads();
    for(int s = 128; s > 0; s >>= 1){
        if(t < s) sh[t] += sh[t + s];
        __syncthreads();
    }
    if(t == 0 && sh[0] > 0) atomicAdd(flag, sh[0]);
}
#define GETM(modeptr) (((*(modeptr)) > 64) ? 1 : 0)

// ---------- small utility kernels ----------
__global__ void fill_f32(float* p, float v, int n){
    int i = blockIdx.x * blockDim.x + threadIdx.x;
    if(i < n) p[i] = v;
}

// token2map scatter
__global__ __launch_bounds__(256) void scatter_map(const void* x, const void* loc,
                                                   const int* idx_agg, float* acc, float* cnt,
                                                   const int* mode){
    int m = GETM(mode);
    int bn = blockIdx.x;                 // 0..16383
    int b = bn >> 12;
    float lx = ldin(loc, (long)bn * 2 + 0, m);
    float ly = ldin(loc, (long)bn * 2 + 1, m);
    int p = pix_idx(lx, ly, 32.f, 64);
    int ia = idx_agg[bn] & 4095;
    long src = ((long)(b << 12) + ia) * 256;
    float* dst = acc + ((size_t)(b << 12) + p) * 256;
    int t = threadIdx.x;                 // 256 = C
    unsafeAtomicAdd(&dst[t], ldin(x, src + t, m));
    if(t == 0) unsafeAtomicAdd(&cnt[(b << 12) + p], 1.0f);
}

__global__ void divide_map(float* xmap, const float* cnt, int n){
    int i = blockIdx.x * 256 + threadIdx.x;
    if(i < n) xmap[i] = xmap[i] / (cnt[i >> 8] + 1e-6f);
}

// ---------- conv C init with bias ----------
__global__ void init_convo(float* convo, const void* bias, const int* mode){
    int m = GETM(mode);
    int e = blockIdx.x * 256 + threadIdx.x;   // 2,097,152
    convo[e] = ldin(bias, e & 511, m);
}

// ================== MFMA infra (fp16 2-way split, 3-product exact emulation) ==================
typedef _Float16 half8 __attribute__((ext_vector_type(8)));
typedef float f32x16 __attribute__((ext_vector_type(16)));
#define MFMA16(A,B,C) __builtin_amdgcn_mfma_f32_32x32x16_f16(A,B,C,0,0,0)

__device__ inline void gld16(const unsigned short* g, unsigned short* l){
    __builtin_amdgcn_global_load_lds((const __attribute__((address_space(1))) unsigned int*)g,
                                     (__attribute__((address_space(3))) unsigned int*)l, 16, 0, 0);
}
__device__ inline void split2w(const float* v, unsigned* hw, unsigned* lw){
#pragma unroll
    for(int u = 0; u < 4; ++u){
        _Float16 h0 = (_Float16)v[2*u];
        _Float16 l0 = (_Float16)(v[2*u] - (float)h0);
        _Float16 h1 = (_Float16)v[2*u+1];
        _Float16 l1 = (_Float16)(v[2*u+1] - (float)h1);
        hw[u] = (((unsigned)__builtin_bit_cast(unsigned short, h1)) << 16) | __builtin_bit_cast(unsigned short, h0);
        lw[u] = (((unsigned)__builtin_bit_cast(unsigned short, l1)) << 16) | __builtin_bit_cast(unsigned short, l0);
    }
}

// split kernel: xtok f32 [16384][512] -> SP[2][64][16384][8] fp16 bits
__global__ __launch_bounds__(256) void split2(const float* xt, unsigned short* SP){
    int e = blockIdx.x * 256 + threadIdx.x;   // 1,048,576 = 64 groups * 16384 rows
    int g = e >> 14, row = e & 16383;
    const float* src = xt + (size_t)row * 512 + g * 8;
    float4 a = *(const float4*)src;
    float4 b = *(const float4*)(src + 4);
    float v[8] = {a.x, a.y, a.z, a.w, b.x, b.y, b.z, b.w};
    unsigned hw[4], lw[4];
    split2w(v, hw, lw);
    *(uint4*)(void*)(SP + ((size_t)g * 16384 + row) * 8) = make_uint4(hw[0], hw[1], hw[2], hw[3]);
    *(uint4*)(void*)(SP + ((size_t)(64 + g) * 16384 + row) * 8) = make_uint4(lw[0], lw[1], lw[2], lw[3]);
}

// xmap f32 [4][64][64][256] -> XMS[2][32][4*66*66][8] f16 (zero-padded 66x66 grid)
__global__ __launch_bounds__(256) void split_xmap(const float* xmap, unsigned short* XMS){
    int e = blockIdx.x * 256 + threadIdx.x;      // 557,568 = 17424*32
    int g = e & 31, pix = e >> 5;
    int b = pix / 4356, r = pix - b * 4356;
    int py = r / 66, px = r - py * 66;
    float v[8];
    if(py >= 1 && py <= 64 && px >= 1 && px <= 64){
        const float* src = xmap + ((size_t)(b << 12) + ((py - 1) << 6) + (px - 1)) * 256 + g * 8;
        float4 a = *(const float4*)src;
        float4 c = *(const float4*)(src + 4);
        v[0]=a.x; v[1]=a.y; v[2]=a.z; v[3]=a.w; v[4]=c.x; v[5]=c.y; v[6]=c.z; v[7]=c.w;
    } else {
#pragma unroll
        for(int u = 0; u < 8; ++u) v[u] = 0.f;
    }
    unsigned hw[4], lw[4];
    split2w(v, hw, lw);
    *(uint4*)(void*)(XMS + ((size_t)g * 17424 + pix) * 8) = make_uint4(hw[0], hw[1], hw[2], hw[3]);
    *(uint4*)(void*)(XMS + ((size_t)(32 + g) * 17424 + pix) * 8) = make_uint4(lw[0], lw[1], lw[2], lw[3]);
}

// conv_w [2304][512] -> CWT[2][288][512][8] (k-transposed: row j holds its k-vector)
__global__ __launch_bounds__(256) void split_cw(const void* cwp, unsigned short* CWT, const int* mode){
    int m = GETM(mode);
    int e = blockIdx.x * 256 + threadIdx.x;   // 147,456 = 288*512
    int col = e & 511, kg = e >> 9;
    float v[8];
#pragma unroll
    for(int u = 0; u < 8; ++u) v[u] = ldin(cwp, (long)(kg * 8 + u) * 512 + col, m);
    unsigned hw[4], lw[4];
    split2w(v, hw, lw);
    *(uint4*)(void*)(CWT + ((size_t)kg * 512 + col) * 8) = make_uint4(hw[0], hw[1], hw[2], hw[3]);
    *(uint4*)(void*)(CWT + ((size_t)(288 + kg) * 512 + col) * 8) = make_uint4(lw[0], lw[1], lw[2], lw[3]);
}

// skip_w [256][512] -> SWT[2][32][512][8]
__global__ __launch_bounds__(256) void split_sw(const void* swp, unsigned short* SWT, const int* mode){
    int m = GETM(mode);
    int e = blockIdx.x * 256 + threadIdx.x;   // 16,384 = 32*512
    int col = e & 511, kg = e >> 9;
    float v[8];
#pragma unroll
    for(int u = 0; u < 8; ++u) v[u] = ldin(swp, (long)(kg * 8 + u) * 512 + col, m);
    unsigned hw[4], lw[4];
    split2w(v, hw, lw);
    *(uint4*)(void*)(SWT + ((size_t)kg * 512 + col) * 8) = make_uint4(hw[0], hw[1], hw[2], hw[3]);
    *(uint4*)(void*)(SWT + ((size_t)(32 + kg) * 512 + col) * 8) = make_uint4(lw[0], lw[1], lw[2], lw[3]);
}

// x (mode-typed) [16384][256] -> XS[2][32][16384][8]
__global__ __launch_bounds__(256) void split_x(const void* xp, unsigned short* XS, const int* mode){
    int m = GETM(mode);
    int e = blockIdx.x * 256 + threadIdx.x;   // 524,288 = 32*16384
    int g = e & 31, row = e >> 5;
    long base = (long)row * 256 + g * 8;
    float v[8];
#pragma unroll
    for(int u = 0; u < 8; ++u) v[u] = ldin(xp, base + u, m);
    unsigned hw[4], lw[4];
    split2w(v, hw, lw);
    *(uint4*)(void*)(XS + ((size_t)g * 16384 + row) * 8) = make_uint4(hw[0], hw[1], hw[2], hw[3]);
    *(uint4*)(void*)(XS + ((size_t)(32 + g) * 16384 + row) * 8) = make_uint4(lw[0], lw[1], lw[2], lw[3]);
}

// shared MFMA inner math for conv/skip: consumes 32KB tile [s][tile][gl][128row][8] via STV
#define MFMA_CORE(STV) \
    _Pragma("unroll") \
    for(int ks = 0; ks < 2; ++ks){ \
        int kg = (ks << 1) + kh; \
        half8 ah0 = (STV)[kg*128 + rb];        half8 ah1 = (STV)[kg*128 + rb + 32]; \
        half8 bh0 = (STV)[(4+kg)*128 + cbx];   half8 bh1 = (STV)[(4+kg)*128 + cbx + 32]; \
        half8 al0 = (STV)[(8+kg)*128 + rb];    half8 al1 = (STV)[(8+kg)*128 + rb + 32]; \
        half8 bl0 = (STV)[(12+kg)*128 + cbx];  half8 bl1 = (STV)[(12+kg)*128 + cbx + 32]; \
        acc00 = MFMA16(ah0,bh0,acc00); acc00 = MFMA16(ah0,bl0,acc00); acc00 = MFMA16(al0,bh0,acc00); \
        acc01 = MFMA16(ah0,bh1,acc01); acc01 = MFMA16(ah0,bl1,acc01); acc01 = MFMA16(al0,bh1,acc01); \
        acc10 = MFMA16(ah1,bh0,acc10); acc10 = MFMA16(ah1,bl0,acc10); acc10 = MFMA16(al1,bh0,acc10); \
        acc11 = MFMA16(ah1,bh1,acc11); acc11 = MFMA16(ah1,bl1,acc11); acc11 = MFMA16(al1,bh1,acc11); \
    }

#define MFMA_STEP { const half8* stv_ = (const half8*)stage; MFMA_CORE(stv_) }

// ---------- conv3x3 s2 p1 via im2col on MFMA: 128x128 tile, K-split x4, atomic epilogue ----------
__global__ __launch_bounds__(256) void conv_mfma(const unsigned short* XMS, const unsigned short* CWT,
                                                 float* C){
    __shared__ __align__(16) unsigned short stage[16384];
    int t = threadIdx.x;
    int j0 = blockIdx.x * 128;                // 4
    int i0 = blockIdx.y * 128;                // 32
    int kz = blockIdx.z;                      // 4 (K chunks of 576)
    int w = t >> 6, lane = t & 63, kh = lane >> 5;
    int row = t & 127, glo = t >> 7;
    int p = i0 + row;
    int b = p >> 10, r = p & 1023, oy = r >> 5, ox = r & 31;
    long pixbase = (long)b * 4356 + oy * 132 + ox * 2;
    long colv = (long)(j0 + row) * 8;
    f32x16 acc00, acc01, acc10, acc11;
#pragma unroll
    for(int q = 0; q < 16; ++q){ acc00[q]=0.f; acc01[q]=0.f; acc10[q]=0.f; acc11[q]=0.f; }
    unsigned short* ldsb = stage + (size_t)(t & 192) * 8;
    int rb = ((w >> 1) << 6) + (lane & 31);
    int cbx = ((w & 1) << 6) + (lane & 31);
    for(int c_ = 0; c_ < 18; ++c_){
        int cg = kz * 18 + c_;
        int tap = cg >> 3;                    // 0..8 (chunk of 32 stays within one tap)
        int tdiv = tap / 3;
        long toff = (long)tdiv * 66 + (tap - tdiv * 3);
        int c8 = (cg & 7) << 2;               // channel kgroup base
        long apix = (pixbase + toff) * 8;
        const unsigned short* a0 = XMS + (size_t)(c8 + glo)          * 139392 + apix;
        const unsigned short* a1 = XMS + (size_t)(c8 + 2 + glo)      * 139392 + apix;
        const unsigned short* a4 = XMS + (size_t)(32 + c8 + glo)     * 139392 + apix;
        const unsigned short* a5 = XMS + (size_t)(32 + c8 + 2 + glo) * 139392 + apix;
        const unsigned short* b2 = CWT + (size_t)((cg << 2) + glo)           * 4096 + colv;
        const unsigned short* b3 = CWT + (size_t)((cg << 2) + 2 + glo)       * 4096 + colv;
        const unsigned short* b6 = CWT + (size_t)(288 + (cg << 2) + glo)     * 4096 + colv;
        const unsigned short* b7 = CWT + (size_t)(288 + (cg << 2) + 2 + glo) * 4096 + colv;
        __syncthreads();
        gld16(a0, ldsb);          gld16(a1, ldsb + 2048);
        gld16(b2, ldsb + 4096);   gld16(b3, ldsb + 6144);
        gld16(a4, ldsb + 8192);   gld16(a5, ldsb + 10240);
        gld16(b6, ldsb + 12288);  gld16(b7, ldsb + 14336);
        __syncthreads();
        MFMA_STEP
    }
    int rbase = i0 + ((w >> 1) << 6);
    int cbase = j0 + ((w & 1) << 6) + (lane & 31);
#pragma unroll
    for(int q = 0; q < 16; ++q){
        int rL = (q & 3) + ((q >> 2) << 3) + (kh << 2);
        unsafeAtomicAdd(&C[(size_t)(rbase + rL) * 512 + cbase],           acc00[q]);
        unsafeAtomicAdd(&C[(size_t)(rbase + rL) * 512 + cbase + 32],      acc01[q]);
        unsafeAtomicAdd(&C[(size_t)(rbase + 32 + rL) * 512 + cbase],      acc10[q]);
        unsafeAtomicAdd(&C[(size_t)(rbase + 32 + rL) * 512 + cbase + 32], acc11[q]);
    }
}

// ---------- skip GEMM on MFMA: x[16384,256] @ skip_w -> xtok (direct store) ----------
__global__ __launch_bounds__(256) void skip_mfma(const unsigned short* XS, const unsigned short* SWT,
                                                 float* C){
    __shared__ __align__(16) unsigned short stage[16384];
    int t = threadIdx.x;
    int j0 = blockIdx.x * 128;                // 4
    int i0 = blockIdx.y * 128;                // 128
    int w = t >> 6, lane = t & 63, kh = lane >> 5;
    int row = t & 127, glo = t >> 7;
    long arow = (long)(i0 + row) * 8;
    long colv = (long)(j0 + row) * 8;
    f32x16 acc00, acc01, acc10, acc11;
#pragma unroll
    for(int q = 0; q < 16; ++q){ acc00[q]=0.f; acc01[q]=0.f; acc10[q]=0.f; acc11[q]=0.f; }
    unsigned short* ldsb = stage + (size_t)(t & 192) * 8;
    int rb = ((w >> 1) << 6) + (lane & 31);
    int cbx = ((w & 1) << 6) + (lane & 31);
    for(int c_ = 0; c_ < 8; ++c_){
        const unsigned short* a0 = XS + (size_t)((c_ << 2) + glo)          * 131072 + arow;
        const unsigned short* a1 = XS + (size_t)((c_ << 2) + 2 + glo)      * 131072 + arow;
        const unsigned short* a4 = XS + (size_t)(32 + (c_ << 2) + glo)     * 131072 + arow;
        const unsigned short* a5 = XS + (size_t)(32 + (c_ << 2) + 2 + glo) * 131072 + arow;
        const unsigned short* b2 = SWT + (size_t)((c_ << 2) + glo)          * 4096 + colv;
        const unsigned short* b3 = SWT + (size_t)((c_ << 2) + 2 + glo)      * 4096 + colv;
        const unsigned short* b6 = SWT + (size_t)(32 + (c_ << 2) + glo)     * 4096 + colv;
        const unsigned short* b7 = SWT + (size_t)(32 + (c_ << 2) + 2 + glo) * 4096 + colv;
        __syncthreads();
        gld16(a0, ldsb);          gld16(a1, ldsb + 2048);
        gld16(b2, ldsb + 4096);   gld16(b3, ldsb + 6144);
        gld16(a4, ldsb + 8192);   gld16(a5, ldsb + 10240);
        gld16(b6, ldsb + 12288);  gld16(b7, ldsb + 14336);
        __syncthreads();
        MFMA_STEP
    }
    int rbase = i0 + ((w >> 1) << 6);
    int cbase = j0 + ((w & 1) << 6) + (lane & 31);
#pragma unroll
    for(int q = 0; q < 16; ++q){
        int rL = (q & 3) + ((q >> 2) << 3) + (kh << 2);
        C[(size_t)(rbase + rL) * 512 + cbase]           = acc00[q];
        C[(size_t)(rbase + rL) * 512 + cbase + 32]      = acc01[q];
        C[(size_t)(rbase + 32 + rL) * 512 + cbase]      = acc10[q];
        C[(size_t)(rbase + 32 + rL) * 512 + cbase + 32] = acc11[q];
    }
}

// ---------- map2token ----------
__global__ void wsum_add(const int* idx_agg, const void* aggw, float* wsum, const int* mode){
    int m = GETM(mode);
    int e = blockIdx.x * 256 + threadIdx.x;   // 16384
    int b = e >> 12;
    unsafeAtomicAdd(&wsum[(b << 12) + (idx_agg[e] & 4095)], ldin(aggw, e, m));
}

__global__ __launch_bounds__(128) void scatter_tok(const void* loc, const int* idx_agg,
                                                   const void* aggw, const float* convo,
                                                   const float* wsum, float* xtok, const int* mode){
    int m = GETM(mode);
    int bn = blockIdx.x;
    int b = bn >> 12;
    float lx = ldin(loc, (long)bn * 2 + 0, m);
    float ly = ldin(loc, (long)bn * 2 + 1, m);
    int p = pix_idx(lx, ly, 16.f, 32);
    int tk = idx_agg[bn] & 4095;
    float w = ldin(aggw, bn, m);
    float scale = w / wsum[(b << 12) + tk];
    const float* pv = convo + ((size_t)(b << 10) + p) * 512;
    float* dst = xtok + ((size_t)(b << 12) + tk) * 512;
    int c = threadIdx.x * 4;
    float4 v = *(const float4*)&pv[c];
    unsafeAtomicAdd(&dst[c + 0], v.x * scale);
    unsafeAtomicAdd(&dst[c + 1], v.y * scale);
    unsafeAtomicAdd(&dst[c + 2], v.z * scale);
    unsafeAtomicAdd(&dst[c + 3], v.w * scale);
}

// ---------- fused layernorm + conf + weight + x2 ----------
__global__ __launch_bounds__(128) void ln_conf(float* xtok, const void* g_, const void* b_,
                                               const void* cw_, const void* cb_,
                                               float* wgt, float* x2a, const int* mode){
    int m = GETM(mode);
    int row = blockIdx.x;        // 0..16383
    int t = threadIdx.x;         // 128
    float* xr = xtok + (size_t)row * 512;
    int c0 = t * 4;
    float4 v = *(const float4*)&xr[c0];
    float xv[4] = {v.x, v.y, v.z, v.w};
    __shared__ float red[2];
    __shared__ float red2[4];
    float s = xv[0] + xv[1] + xv[2] + xv[3];
    s = wred_add(s);
    if((t & 63) == 0) red[t >> 6] = s;
    __syncthreads();
    float mean = (red[0] + red[1]) * (1.f / 512.f);
    __syncthreads();
    float xc[4];
#pragma unroll
    for(int u = 0; u < 4; ++u) xc[u] = xv[u] - mean;
    float q = xc[0]*xc[0] + xc[1]*xc[1] + xc[2]*xc[2] + xc[3]*xc[3];
    q = wred_add(q);
    if((t & 63) == 0) red[t >> 6] = q;
    __syncthreads();
    float var = (red[0] + red[1]) * (1.f / 512.f);
    float rs = 1.0f / sqrtf(var + 1e-5f);
    float y[4];
#pragma unroll
    for(int u = 0; u < 4; ++u)
        y[u] = xc[u] * rs * ldin(g_, c0 + u, m) + ldin(b_, c0 + u, m);
    float4 st; st.x = y[0]; st.y = y[1]; st.z = y[2]; st.w = y[3];
    *(float4*)&xr[c0] = st;
    float cf = y[0]*ldin(cw_, c0+0, m) + y[1]*ldin(cw_, c0+1, m)
             + y[2]*ldin(cw_, c0+2, m) + y[3]*ldin(cw_, c0+3, m);
    float qq = y[0]*y[0] + y[1]*y[1] + y[2]*y[2] + y[3]*y[3];
    cf = wred_add(cf);
    qq = wred_add(qq);
    if((t & 63) == 0){ red2[t >> 6] = cf; red2[2 + (t >> 6)] = qq; }
    __syncthreads();
    if(t == 0){
        wgt[row] = expf(red2[0] + red2[1] + ldin(cb_, 0, m));
        x2a[row] = red2[2] + red2[3];
    }
}

// ================== 8-wave Gram core: 512 threads, counted-vmcnt double buffer (T4) ==========
// BK=32 with the two 32KB halves as a true dbuf. Per chunk: issue next chunk's 4 gld16 into
// buf^1, s_waitcnt vmcnt(4) (previous chunk landed, next stays IN FLIGHT across compute),
// raw s_barrier, 12 MFMAs, raw s_barrier (fences buffer reuse; each wave's ds_reads are
// consumed by its issued MFMAs before it arrives -> no drain needed). Loads retire in order
// (m135); if(c<15) is wave-uniform so barrier counts match. Chunk order 0..15 and per-chunk
// MFMA sequence unchanged -> bit-identical d2.
#define INITP8(R, AEXPR) const unsigned short* p##R; { \
    int cell = t + ((R) << 9); int row = cell & 127; int gl = (cell >> 7) & 3; \
    int tile = (cell >> 9) & 1; int sp_ = cell >> 10; \
    int grow = (z << 12) + (tile ? (j0 + row) : (AEXPR)); \
    p##R = SP + (size_t)((sp_ << 6) + gl) * 131072 + (size_t)grow * 8; }

#define GRAM8_CORE(AEXPR) \
    int w = t >> 6; int lane = t & 63; int kh = lane >> 5; \
    int ra = ((w & 3) << 5) + (lane & 31); \
    int cb = ((w >> 2) << 6) + (lane & 31); \
    f32x16 acc0, acc1; \
    _Pragma("unroll") for(int q_ = 0; q_ < 16; ++q_){ acc0[q_]=0.f; acc1[q_]=0.f; } \
    INITP8(0, AEXPR) INITP8(1, AEXPR) INITP8(2, AEXPR) INITP8(3, AEXPR) \
    { \
        unsigned short* ldsb = stage + (size_t)(t & 448) * 8; \
        gld16(p0, ldsb);        gld16(p1, ldsb + 4096); \
        gld16(p2, ldsb + 8192); gld16(p3, ldsb + 12288); \
        p0 += 524288; p1 += 524288; p2 += 524288; p3 += 524288; \
        for(int c_ = 0; c_ < 16; ++c_){ \
            if(c_ < 15){ \
                unsigned short* ldsw = ldsb + (((c_ + 1) & 1) << 14); \
                gld16(p0, ldsw);        gld16(p1, ldsw + 4096); \
                gld16(p2, ldsw + 8192); gld16(p3, ldsw + 12288); \
                p0 += 524288; p1 += 524288; p2 += 524288; p3 += 524288; \
                asm volatile("s_waitcnt vmcnt(4)" ::: "memory"); \
            } else { \
                asm volatile("s_waitcnt vmcnt(0)" ::: "memory"); \
            } \
            __builtin_amdgcn_s_barrier(); \
            asm volatile("" ::: "memory"); \
            const half8* stv = (const half8*)(stage + ((c_ & 1) << 14)); \
            _Pragma("unroll") \
            for(int ks = 0; ks < 2; ++ks){ \
                int kg = (ks << 1) + kh; \
                half8 ah  = stv[kg*128 + ra]; \
                half8 al  = stv[(8+kg)*128 + ra]; \
                half8 bh0 = stv[(4+kg)*128 + cb];   half8 bh1 = stv[(4+kg)*128 + cb + 32]; \
                half8 bl0 = stv[(12+kg)*128 + cb];  half8 bl1 = stv[(12+kg)*128 + cb + 32]; \
                acc0 = MFMA16(ah,bh0,acc0); acc0 = MFMA16(ah,bl0,acc0); acc0 = MFMA16(al,bh0,acc0); \
                acc1 = MFMA16(ah,bh1,acc1); acc1 = MFMA16(ah,bl1,acc1); acc1 = MFMA16(al,bh1,acc1); \
            } \
            asm volatile("" ::: "memory"); \
            __builtin_amdgcn_s_barrier(); \
        } \
    }

// dump the wave's two 32x32 quadrants into the 64x128 f32 window when its row-block is in phase
#define DUMP_ONE8(ACC, N) { \
    int coln = ((w >> 2) << 6) + ((N) << 5) + (lane & 31); \
    float xc2v = x2c[coln]; \
    _Pragma("unroll") for(int q = 0; q < 16; ++q){ \
        int rLw = (((w & 3) & 1) << 5) + (q & 3) + ((q >> 2) << 3) + (kh << 2); \
        d2t[rLw * 128 + coln] = x2r[(ph << 6) + rLw] + xc2v - 2.0f * ACC[q]; } }

#define DUMP8 if(((w & 3) >> 1) == ph){ DUMP_ONE8(acc0,0) DUMP_ONE8(acc1,1) }

// 5-list bitonic merge step via shfl_xor (lists sorted ascending; keeps 5 smallest)
#define MERGE5(B5, MK) { \
    float o0=__shfl_xor(B5[0],MK), o1=__shfl_xor(B5[1],MK), o2=__shfl_xor(B5[2],MK), \
          o3=__shfl_xor(B5[3],MK), o4=__shfl_xor(B5[4],MK); \
    B5[0]=fminf(B5[0],o4); B5[1]=fminf(B5[1],o3); B5[2]=fminf(B5[2],o2); \
    B5[3]=fminf(B5[3],o1); B5[4]=fminf(B5[4],o0); \
    sort5n(B5); }

// triangular block map: q -> (bi <= bj)
#define TRI_MAP(q, bi, bj)                                         \
    int bj = (int)((sqrtf(8.0f * (q) + 1.0f) - 1.0f) * 0.5f);      \
    while((bj + 1) * (bj + 2) / 2 <= (q)) bj++;                    \
    while(bj * (bj + 1) / 2 > (q)) bj--;                           \
    int bi = (q) - bj * (bj + 1) / 2;

// ---------- Pass A: top5 + max per row/col ----------
__global__ __launch_bounds__(512, 2) void gramA10(const unsigned short* SP, const float* x2b,
                                                  float* part5, float* pmax){
    __shared__ __align__(16) unsigned short stage[32768];   // 64KB dbuf; front aliased as d2
    __shared__ float x2r[128], x2c[128];
    float* d2t = (float*)stage;
    int z = blockIdx.z;
    TRI_MAP((int)blockIdx.x, bi, bj)
    int i0 = bi * 128, j0 = bj * 128;
    int t = threadIdx.x;
    if(t < 128) x2r[t] = x2b[(z << 12) + i0 + t];
    else if(t < 256) x2c[t - 128] = x2b[(z << 12) + j0 + (t - 128)];
    GRAM8_CORE(i0 + row)
    float c5[5] = {FLTMAX, FLTMAX, FLTMAX, FLTMAX, FLTMAX};
    float cmx = -FLTMAX;
    int colc = t >> 2, rhc = t & 3;
    for(int ph = 0; ph < 2; ++ph){
        __syncthreads();
        DUMP8
        __syncthreads();
        {   // row scan: 8 threads/row, 16 staggered cols each; 3-level shfl bitonic merge
            int rr = t >> 3, ch = t & 7;
            float b5[5] = {FLTMAX, FLTMAX, FLTMAX, FLTMAX, FLTMAX};
            float mx = -FLTMAX;
#pragma unroll
            for(int c = 0; c < 16; ++c){
                int col = (ch << 4) + ((rr + c) & 15);
                float v = d2t[rr * 128 + col];
                ins5(b5, v); mx = fmaxf(mx, v);
            }
#pragma unroll
            for(int lvl = 0; lvl < 3; ++lvl){
                int mk = 1 << lvl;
                MERGE5(b5, mk)
                mx = fmaxf(mx, __shfl_xor(mx, mk));
            }
            if(ch == 0){
                size_t rowg = (size_t)(z << 12) + i0 + (ph << 6) + rr;
                size_t o = (rowg * 32 + bj) * 5;
                part5[o]=b5[0]; part5[o+1]=b5[1]; part5[o+2]=b5[2]; part5[o+3]=b5[3]; part5[o+4]=b5[4];
                pmax[rowg * 32 + bj] = mx;
            }
        }
        if(bi != bj){   // col accumulate: 4 threads/col, 16 rows each per phase
#pragma unroll
            for(int r2 = 0; r2 < 16; ++r2){
                float v = d2t[(((rhc << 4) + r2) << 7) + colc];
                ins5(c5, v); cmx = fmaxf(cmx, v);
            }
        }
    }
    if(bi != bj){
#pragma unroll
        for(int lvl = 0; lvl < 2; ++lvl){
            int mk = 1 << lvl;
            MERGE5(c5, mk)
            cmx = fmaxf(cmx, __shfl_xor(cmx, mk));
        }
        if(rhc == 0){
            size_t rowg = (size_t)(z << 12) + j0 + colc;
            size_t o = (rowg * 32 + bi) * 5;
            part5[o]=c5[0]; part5[o+1]=c5[1]; part5[o+2]=c5[2]; part5[o+3]=c5[3]; part5[o+4]=c5[4];
            pmax[rowg * 32 + bi] = cmx;
        }
    }
}

// ---------- reduceA4: wave-parallel bitonic top5 merge; NO atomics (block max -> bmax) ----------
__global__ __launch_bounds__(256) void reduceA4(const float* part5, const float* pmax,
                                                float* dens_b, float* bmax){
    __shared__ float wmx[4];
    int t = threadIdx.x;
    int wv = t >> 6, lane = t & 63;
    int bi = blockIdx.x * 4 + wv;             // token 0..16383, grid 4096 (block within one batch)
    int l = lane & 31;                        // both 32-halves compute identically
    const float* p = part5 + ((size_t)bi * 32 + l) * 5;
    float a[5] = {p[0], p[1], p[2], p[3], p[4]};
    float mm = pmax[(size_t)bi * 32 + l];
#pragma unroll
    for(int lvl = 0; lvl < 5; ++lvl){
        int mask = 1 << lvl;
        MERGE5(a, mask)
        mm = fmaxf(mm, __shfl_xor(mm, mask));
    }
    if(lane == 0){
        const float sqrtC = 22.627416997969522f;
        float s = 0.f;
#pragma unroll
        for(int q = 0; q < 5; ++q){
            float d = sqrtf(fmaxf(a[q], 0.f)) / sqrtC;
            s = s + d * d;
        }
        dens_b[bi] = expf(-(s / 5.0f));
        wmx[wv] = mm;
    }
    __syncthreads();
    if(t == 0)
        bmax[blockIdx.x] = fmaxf(fmaxf(fmaxf(wmx[0], wmx[1]), fmaxf(wmx[2], wmx[3])), 0.f);
}

// per-batch dmax: reduce 1024 block maxes -> dmaxf[z] (written as float; reduceB3 reads bits)
__global__ __launch_bounds__(256) void dmax_k(const float* bmax, float* dmaxf){
    __shared__ float sm[4];
    int z = blockIdx.x, t = threadIdx.x;
    const float* src = bmax + (z << 10);
    float m = fmaxf(fmaxf(src[t], src[t + 256]), fmaxf(src[t + 512], src[t + 768]));
    for(int o = 32; o > 0; o >>= 1) m = fmaxf(m, __shfl_down(m, o));
    if((t & 63) == 0) sm[t >> 6] = m;
    __syncthreads();
    if(t == 0) dmaxf[z] = fmaxf(fmaxf(sm[0], sm[1]), fmaxf(sm[2], sm[3]));
}

// ---------- Pass B: min dist to any higher-density token ----------
__global__ __launch_bounds__(512, 2) void gramB10(const unsigned short* SP, const float* x2b,
                                                  const float* dens_b, float* pmin){
    __shared__ __align__(16) unsigned short stage[32768];
    __shared__ float x2r[128], x2c[128], densr[128], densc[128];
    float* d2t = (float*)stage;
    int z = blockIdx.z;
    TRI_MAP((int)blockIdx.x, bi, bj)
    int i0 = bi * 128, j0 = bj * 128;
    int t = threadIdx.x;
    if(t < 128){ x2r[t] = x2b[(z << 12) + i0 + t]; densr[t] = dens_b[(z << 12) + i0 + t]; }
    else if(t < 256){ x2c[t-128] = x2b[(z << 12) + j0 + (t-128)]; densc[t-128] = dens_b[(z << 12) + j0 + (t-128)]; }
    GRAM8_CORE(i0 + row)
    float colmin = FLTMAX;
    int colc = t >> 2, rhc = t & 3;
    float dcc = 0.f;
    for(int ph = 0; ph < 2; ++ph){
        __syncthreads();
        DUMP8
        __syncthreads();
        {
            int rr = t >> 3, ch = t & 7;
            float dr = densr[(ph << 6) + rr];
            float pm = FLTMAX;
#pragma unroll
            for(int c = 0; c < 16; ++c){
                int col = (ch << 4) + ((rr + c) & 15);
                float v = d2t[rr * 128 + col];
                if(densc[col] > dr) pm = fminf(pm, v);
            }
#pragma unroll
            for(int lvl = 0; lvl < 3; ++lvl) pm = fminf(pm, __shfl_xor(pm, 1 << lvl));
            if(ch == 0) pmin[((size_t)(z << 12) + i0 + (ph << 6) + rr) * 32 + bj] = pm;
        }
        if(bi != bj){
            dcc = densc[colc];
#pragma unroll
            for(int r2 = 0; r2 < 16; ++r2){
                int rLw = (rhc << 4) + r2;
                float v = d2t[(rLw << 7) + colc];
                if(densr[(ph << 6) + rLw] > dcc) colmin = fminf(colmin, v);
            }
        }
    }
    if(bi != bj){
        colmin = fminf(colmin, __shfl_xor(colmin, 1));
        colmin = fminf(colmin, __shfl_xor(colmin, 2));
        if(rhc == 0) pmin[((size_t)(z << 12) + j0 + colc) * 32 + bi] = colmin;
    }
}

// flat: one thread per token (same fminf chain order as before -> bit-identical)
__global__ __launch_bounds__(256) void reduceB3(const float* pmin, const float* dens_b,
                                                const int* dmax_b, float* score_b){
    int bi = blockIdx.x * 256 + threadIdx.x;  // 0..16383
    float m = FLTMAX;
    for(int c = 0; c < 32; ++c) m = fminf(m, pmin[(size_t)bi * 32 + c]);
    const float sqrtC = 22.627416997969522f;
    float dp;
    if(m == FLTMAX) dp = sqrtf(fmaxf(__int_as_float(dmax_b[bi >> 12]), 0.f)) / sqrtC;
    else            dp = sqrtf(fmaxf(m, 0.f)) / sqrtC;
    score_b[bi] = dp * dens_b[bi];
}

// ---------- Pass C: gathered-center Gram -> per-(token, centerblock) argmin ----------
__global__ __launch_bounds__(512, 2) void gramC10(const unsigned short* SP, const float* x2b,
                                                  const int* idown_b, float* pcd, int* pci){
    __shared__ __align__(16) unsigned short stage[32768];
    __shared__ float x2r[128], x2c[128];
    __shared__ int idzl[128];
    float* d2t = (float*)stage;
    int z = blockIdx.z;
    int s0 = blockIdx.y * 128, j0 = blockIdx.x * 128;
    int t = threadIdx.x;
    if(t < 128) idzl[t] = idown_b[(z << 10) + s0 + t];
    else if(t < 256) x2c[t - 128] = x2b[(z << 12) + j0 + (t - 128)];
    __syncthreads();
    if(t < 128) x2r[t] = x2b[(z << 12) + idzl[t]];
    GRAM8_CORE(idzl[row])
    const float sqrtC = 22.627416997969522f;
    float bd = FLTMAX; int bsi = 0;
    int colc = t >> 2, rhc = t & 3;
    for(int ph = 0; ph < 2; ++ph){
        __syncthreads();
        DUMP8
        __syncthreads();
#pragma unroll
        for(int r2 = 0; r2 < 16; ++r2){          // rows ascend globally across phases
            int rLw = (rhc << 4) + r2;
            float d2v = d2t[(rLw << 7) + colc];
            float d = sqrtf(fmaxf(d2v, 0.f)) / sqrtC;
            if(d < bd){ bd = d; bsi = (ph << 6) + rLw; }
        }
    }
#pragma unroll
    for(int lvl = 0; lvl < 2; ++lvl){            // merge rhc 0..3; tie -> smaller center row
        int mk = 1 << lvl;
        float od = __shfl_xor(bd, mk);
        int   oi = __shfl_xor(bsi, mk);
        if(od < bd || (od == bd && oi < bsi)){ bd = od; bsi = oi; }
    }
    if(rhc == 0){
        pcd[((size_t)(z << 12) + j0 + colc) * 8 + blockIdx.y] = bd;
        pci[((size_t)(z << 12) + j0 + colc) * 8 + blockIdx.y] = s0 + bsi;
    }
}

__global__ void reduceC2(const float* pcd, const int* pci, int* iclus_b){
    int jg = blockIdx.x * 256 + threadIdx.x;      // 0..16383
    float bd = FLTMAX;
    int bs = 0;
    for(int c = 0; c < 8; ++c){
        float d = pcd[(size_t)jg * 8 + c];
        if(d < bd){ bd = d; bs = pci[(size_t)jg * 8 + c]; }
    }
    iclus_b[jg] = bs;
}

// ---------- bitonic sort (score desc, idx asc) -> top 1024; blockIdx.x = batch ----------
__global__ __launch_bounds__(1024) void sort_topk(const float* score, int* idown){
    __shared__ float ss[4096];
    __shared__ int sid[4096];
    int t = threadIdx.x;
    const float* sc = score + (size_t)blockIdx.x * 4096;
    int* id = idown + (size_t)blockIdx.x * 1024;
    for(int v = t; v < 4096; v += 1024){ ss[v] = sc[v]; sid[v] = v; }
    __syncthreads();
    for(int k = 2; k <= 4096; k <<= 1){
        for(int j = k >> 1; j > 0; j >>= 1){
            for(int v = t; v < 4096; v += 1024){
                int l = v ^ j;
                if(l > v){
                    float sv = ss[v], sl = ss[l];
                    int iv = sid[v], il = sid[l];
                    bool before_lv = (sl > sv) || (sl == sv && il < iv);
                    bool before_vl = (sv > sl) || (sv == sl && iv < il);
                    bool asc = ((v & k) == 0);
                    bool sw = asc ? before_lv : before_vl;
                    if(sw){ ss[v] = sl; ss[l] = sv; sid[v] = il; sid[l] = iv; }
                }
            }
            __syncthreads();
        }
    }
    for(int v = t; v < 1024; v += 1024) id[v] = sid[v];
}

// ---------- merge tokens + outputs (FLOAT32 out) ----------
__global__ void allw_add(const int* iclus, const float* wgt, float* allw){
    int e = blockIdx.x * 256 + threadIdx.x;   // 16384
    int b = e >> 12;
    unsafeAtomicAdd(&allw[(b << 10) + (iclus[e] & 1023)], wgt[e]);
}
__global__ void norm_k(const int* iclus, const float* wgt, const float* allw, float* nw){
    int e = blockIdx.x * 256 + threadIdx.x;
    int b = e >> 12;
    nw[e] = wgt[e] / allw[(b << 10) + (iclus[e] & 1023)];
}
// abuf + per-batch max weight; block-uniform batch -> ONE atomicMax per block
__global__ __launch_bounds__(256) void abuf_k2(const int* idx_agg, const void* aggw, const float* nw,
                                               float* abuf, float* maxw, const int* mode){
    __shared__ float wmx[4];
    int m = GETM(mode);
    int t = threadIdx.x;
    int e = blockIdx.x * 256 + t;
    int b = e >> 12;                          // uniform within block (256 | 4096)
    float a = ldin(aggw, e, m) * nw[(b << 12) + (idx_agg[e] & 4095)];
    abuf[e] = a;
    float mm = a;
    for(int o = 32; o > 0; o >>= 1) mm = fmaxf(mm, __shfl_down(mm, o));
    if((t & 63) == 0) wmx[t >> 6] = mm;
    __syncthreads();
    if(t == 0){
        float bm = fmaxf(fmaxf(wmx[0], wmx[1]), fmaxf(wmx[2], wmx[3]));
        atomicMax((int*)&maxw[b], __float_as_int(bm));
    }
}
__global__ __launch_bounds__(128) void scatter_xdown(const int* iclus, const float* nw,
                                                     const float* xtok, float* xdown){
    int bn = blockIdx.x;           // 0..16383
    int b = bn >> 12;
    int cl = iclus[bn] & 1023;
    float w = nw[bn];
    const float* src = xtok + (size_t)bn * 512;
    float* dst = xdown + ((size_t)(b << 10) + cl) * 512;
    int c = threadIdx.x * 4;
    float4 v = *(const float4*)&src[c];
    unsafeAtomicAdd(&dst[c + 0], v.x * w);
    unsafeAtomicAdd(&dst[c + 1], v.y * w);
    unsafeAtomicAdd(&dst[c + 2], v.z * w);
    unsafeAtomicAdd(&dst[c + 3], v.w * w);
}

__global__ void out0_k(const float* xdown, float* out){
    int e = blockIdx.x * 256 + threadIdx.x;
    if(e < 2097152) out[e] = xdown[e];
}
// fused out1 + out2 (both 16384-elem)
__global__ void out12_k(const int* idx_agg, const int* iclus, const float* abuf,
                        const float* maxw, float* out){
    int e = blockIdx.x * 256 + threadIdx.x;   // 16384
    int b = e >> 12;
    int ic = iclus[(b << 12) + (idx_agg[e] & 4095)];
    out[2097152 + e] = (float)ic;
    out[2097152 + 16384 + e] = abuf[e] / maxw[b];
}

// ---------- launch ----------
extern "C" void kernel_launch(void* const* d_in, const int* in_sizes, int n_in,
                              void* d_out, int out_size, void* d_ws, size_t ws_size,
                              hipStream_t stream){
    (void)in_sizes; (void)n_in; (void)out_size; (void)ws_size;
    const void* x    = d_in[0];
    const void* loc  = d_in[1];
    const int* idx_agg = (const int*)d_in[2];
    const void* aggw = d_in[3];
    const void* cw   = d_in[7];
    const void* cb   = d_in[8];
    const void* sw   = d_in[9];
    const void* lg   = d_in[10];
    const void* lnb  = d_in[11];
    const void* cfw  = d_in[12];
    const void* cfb  = d_in[13];
    float* out = (float*)d_out;

    // Phase-aliased layout, total 21,258,249 floats = 85.0 MB (ws >= 101 MB proven).
    float* ws    = (float*)d_ws;
    float* xtok  = ws;                        // 8,388,608
    float* xmap  = ws + 8388608;              // 4,194,304
    float* convo = ws + 12582912;             // 2,097,152
    float* xdown = ws + 14680064;             // 2,097,152
    unsigned short* SP  = (unsigned short*)(ws + 8388608);    // 16,777,216 shorts
    unsigned short* CWT = (unsigned short*)(ws + 14680064);   // 2,359,296 shorts
    unsigned short* SWT = (unsigned short*)(ws + 15859712);   // 262,144 shorts
    unsigned short* XMS = (unsigned short*)(ws + 16777216);   // 8,921,088 shorts
    unsigned short* XS  = (unsigned short*)(ws + 16777216);   // 8,388,608 shorts
    float* cnt   = ws + 16777216;             // 16,384 (phase 1; reused as bmax[4096] in clustering)
    float* part5 = ws + 16793600;             // 2,621,440
    float* pmaxb = ws + 19415040;             // 524,288
    float* pminb = ws + 19939328;             // 524,288
    float* pcd   = ws + 20463616;             // 131,072
    int*   pci   = (int*)(ws + 20594688);     // 131,072
    float* x2    = ws + 20725760;             // 16,384
    float* wgt   = ws + 20742144;             // 16,384
    float* dens  = ws + 20758528;             // 16,384
    float* score = ws + 20774912;             // 16,384
    float* wsum  = ws + 20791296;             // 16,384
    float* allw  = ws + 20807680;             // 4,096 (adjacent to wsum)
    float* nw    = ws + 20811776;             // 16,384
    float* dmaxf = ws + 21237760;             // 4
    float* maxw  = ws + 21237764;             // 4
    int*   idown = (int*)(ws + 21237768);     // 4,096
    int*   iclus = (int*)(ws + 21241864);     // 16,384
    int*   mode  = (int*)(ws + 21258248);     // 1 (hit count)

    hipMemsetAsync(mode, 0, 4, stream);
    detect_mode<<<64, 256, 0, stream>>>(x, mode);

    hipMemsetAsync(xmap, 0, (size_t)4194304 * 4, stream);
    hipMemsetAsync(cnt, 0, (size_t)16384 * 4, stream);
    hipMemsetAsync(dmaxf, 0, 8 * 4, stream);                         // dmax[4] + maxw[4]

    scatter_map<<<16384, 256, 0, stream>>>(x, loc, idx_agg, xmap, cnt, mode);
    divide_map<<<16384, 256, 0, stream>>>(xmap, cnt, 4194304);

    // conv on MFMA
    split_xmap<<<2178, 256, 0, stream>>>(xmap, XMS);
    split_cw<<<576, 256, 0, stream>>>(cw, CWT, mode);
    init_convo<<<8192, 256, 0, stream>>>(convo, cb, mode);
    conv_mfma<<<dim3(4, 32, 4), 256, 0, stream>>>(XMS, CWT, convo);

    // skip GEMM on MFMA (XS reuses XMS region -> after conv_mfma)
    split_x<<<2048, 256, 0, stream>>>(x, XS, mode);
    split_sw<<<64, 256, 0, stream>>>(sw, SWT, mode);
    skip_mfma<<<dim3(4, 128), 256, 0, stream>>>(XS, SWT, xtok);

    fill_f32<<<80, 256, 0, stream>>>(wsum, 1e-6f, 20480);            // wsum + allw (adjacent)
    wsum_add<<<64, 256, 0, stream>>>(idx_agg, aggw, wsum, mode);
    scatter_tok<<<16384, 128, 0, stream>>>(loc, idx_agg, aggw, convo, wsum, xtok, mode);
    ln_conf<<<16384, 128, 0, stream>>>(xtok, lg, lnb, cfw, cfb, wgt, x2, mode);

    // ---- clustering: fp16-split MFMA Gram, counted-vmcnt dbuf; atomic-free reductions ----
    split2<<<4096, 256, 0, stream>>>(xtok, SP);
    gramA10<<<dim3(528, 1, 4), 512, 0, stream>>>(SP, x2, part5, pmaxb);
    reduceA4<<<4096, 256, 0, stream>>>(part5, pmaxb, dens, cnt);     // cnt reused as bmax[4096]
    dmax_k<<<4, 256, 0, stream>>>(cnt, dmaxf);
    gramB10<<<dim3(528, 1, 4), 512, 0, stream>>>(SP, x2, dens, pminb);
    reduceB3<<<64, 256, 0, stream>>>(pminb, dens, (int*)dmaxf, score);
    sort_topk<<<4, 1024, 0, stream>>>(score, idown);
    gramC10<<<dim3(32, 8, 4), 512, 0, stream>>>(SP, x2, idown, pcd, pci);
    reduceC2<<<64, 256, 0, stream>>>(pcd, pci, iclus);

    hipMemsetAsync(xdown, 0, (size_t)2097152 * 4, stream);           // SP/CWT/SWT dead now

    allw_add<<<64, 256, 0, stream>>>(iclus, wgt, allw);
    norm_k<<<64, 256, 0, stream>>>(iclus, wgt, allw, nw);
    abuf_k2<<<64, 256, 0, stream>>>(idx_agg, aggw, nw, score, maxw, mode);  // score reused as abuf

    scatter_xdown<<<16384, 128, 0, stream>>>(iclus, nw, xtok, xdown);

    out0_k<<<8192, 256, 0, stream>>>(xdown, out);
    out12_k<<<64, 256, 0, stream>>>(idx_agg, iclus, score, maxw, out);
}